// Round 1
// baseline (199.147 us; speedup 1.0000x reference)
//
#include <hip/hip_runtime.h>
#include <cstdint>
#include <cstddef>

// Problem constants: B=4, H=W=32, C=256, N=1024, heads=8, d=32.

// ---------------------------------------------------------------------------
// Kernel 1: X1 = src1 + pe, X2 = src2 + pe
// pe[n,c] = sin(pos * 10000^(-(c&63)/64)),  pos = row+1 (c<128) else col+1
// ---------------------------------------------------------------------------
__global__ __launch_bounds__(256) void pe_add_kernel(
    const float* __restrict__ src1, const float* __restrict__ src2,
    float* __restrict__ X1, float* __restrict__ X2)
{
    int n = blockIdx.x;      // 0..1023
    int c = threadIdx.x;     // 0..255
    int row = n >> 5, col = n & 31;
    float pos = (c < 128) ? (float)(row + 1) : (float)(col + 1);
    int cc = c & 63;
    // 10000^(-cc/64) = exp(-cc * ln(10000)/64)
    float freq = expf(-0.14391156831212787f * (float)cc);
    float pe = sinf(pos * freq);
    for (int b = 0; b < 4; ++b) {
        size_t idx = ((size_t)b * 1024 + n) * 256 + c;
        X1[idx] = src1[idx] + pe;
        X2[idx] = src2[idx] + pe;
    }
}

// ---------------------------------------------------------------------------
// Kernel 2: generic fp32 GEMM  C = A(4096x256) @ W(256xNcols) + bias
// FOLD=1: W'[:,c] = W[:,c] + W[:,c+128], bias likewise (head-sum folding).
// W row stride is always 256. 64x64 tile, 256 threads, 4x4 microtile.
// ---------------------------------------------------------------------------
template<int FOLD>
__global__ __launch_bounds__(256) void gemm64(
    const float* __restrict__ A, const float* __restrict__ W,
    const float* __restrict__ bias, float* __restrict__ C, int Ncols)
{
    __shared__ float As[64][68];
    __shared__ float Bs[64][68];
    int tx = threadIdx.x & 15, ty = threadIdx.x >> 4;
    int rowBase = blockIdx.y * 64;
    int colBase = blockIdx.x * 64;

    float acc[4][4] = {};

    for (int k0 = 0; k0 < 256; k0 += 64) {
        #pragma unroll
        for (int rr = 0; rr < 4; ++rr) {
            int r = ty + rr * 16;
            float4 av = *(const float4*)&A[(size_t)(rowBase + r) * 256 + k0 + tx * 4];
            *(float4*)&As[r][tx * 4] = av;
        }
        #pragma unroll
        for (int rr = 0; rr < 4; ++rr) {
            int kk = ty + rr * 16;
            float4 wv = *(const float4*)&W[(size_t)(k0 + kk) * 256 + colBase + tx * 4];
            if (FOLD) {
                float4 w2 = *(const float4*)&W[(size_t)(k0 + kk) * 256 + colBase + tx * 4 + 128];
                wv.x += w2.x; wv.y += w2.y; wv.z += w2.z; wv.w += w2.w;
            }
            *(float4*)&Bs[kk][tx * 4] = wv;
        }
        __syncthreads();
        #pragma unroll
        for (int kk = 0; kk < 64; ++kk) {
            float a0 = As[ty * 4 + 0][kk];
            float a1 = As[ty * 4 + 1][kk];
            float a2 = As[ty * 4 + 2][kk];
            float a3 = As[ty * 4 + 3][kk];
            float4 bv = *(const float4*)&Bs[kk][tx * 4];
            acc[0][0] += a0 * bv.x; acc[0][1] += a0 * bv.y; acc[0][2] += a0 * bv.z; acc[0][3] += a0 * bv.w;
            acc[1][0] += a1 * bv.x; acc[1][1] += a1 * bv.y; acc[1][2] += a1 * bv.z; acc[1][3] += a1 * bv.w;
            acc[2][0] += a2 * bv.x; acc[2][1] += a2 * bv.y; acc[2][2] += a2 * bv.z; acc[2][3] += a2 * bv.w;
            acc[3][0] += a3 * bv.x; acc[3][1] += a3 * bv.y; acc[3][2] += a3 * bv.z; acc[3][3] += a3 * bv.w;
        }
        __syncthreads();
    }

    #pragma unroll
    for (int i = 0; i < 4; ++i) {
        int r = rowBase + ty * 4 + i;
        float4 o;
        int cb = colBase + tx * 4;
        float b0 = bias[cb + 0], b1 = bias[cb + 1], b2 = bias[cb + 2], b3 = bias[cb + 3];
        if (FOLD) {
            b0 += bias[cb + 128]; b1 += bias[cb + 129]; b2 += bias[cb + 130]; b3 += bias[cb + 131];
        }
        o.x = acc[i][0] + b0; o.y = acc[i][1] + b1; o.z = acc[i][2] + b2; o.w = acc[i][3] + b3;
        *(float4*)&C[(size_t)r * Ncols + cb] = o;
    }
}

// ---------------------------------------------------------------------------
// Kernel 3: 3x3 SAME conv on K channels 128..191 (B,32,32,64)->(B,32,32,64)
// block = 256 threads = 4 pixels x 64 out-channels; grid = B*1024/4 = 1024
// ---------------------------------------------------------------------------
__global__ __launch_bounds__(256) void conv3x3_kernel(
    const float* __restrict__ Kbuf, const float* __restrict__ cw,
    const float* __restrict__ cb, float* __restrict__ CONV)
{
    __shared__ float in_s[3][6][64];   // rows y-1..y+1, cols x0-1..x0+4
    int blk = blockIdx.x;
    int b = blk >> 8;           // /256
    int ng = blk & 255;         // pixel-group within image
    int n0 = ng * 4;
    int y = n0 >> 5;
    int x0 = n0 & 31;           // multiple of 4
    int tid = threadIdx.x;

    for (int idx = tid; idx < 3 * 6 * 64; idx += 256) {
        int ci = idx & 63;
        int rem = idx >> 6;
        int rx = rem % 6;
        int ry = rem / 6;
        int gy = y - 1 + ry;
        int gx = x0 - 1 + rx;
        float v = 0.f;
        if (gy >= 0 && gy < 32 && gx >= 0 && gx < 32)
            v = Kbuf[((size_t)(b * 1024 + gy * 32 + gx)) * 256 + 128 + ci];
        in_s[ry][rx][ci] = v;
    }
    __syncthreads();

    int px = tid >> 6;   // 0..3
    int co = tid & 63;
    float acc = cb[co];
    #pragma unroll
    for (int ky = 0; ky < 3; ++ky)
        #pragma unroll
        for (int kx = 0; kx < 3; ++kx)
            for (int ci = 0; ci < 64; ++ci)
                acc += in_s[ky][px + kx][ci] * cw[(((ky * 3 + kx) * 64 + ci) << 6) + co];

    CONV[((size_t)(b * 1024 + n0 + px)) << 6 | co] = acc;
}

// ---------------------------------------------------------------------------
// Kernel 4: attention. One block = (b, head, 32 query rows). Flash-style
// over m-tiles of 64. 256 threads: thread = (row = tid>>3, dgroup = tid&7).
// ---------------------------------------------------------------------------
__global__ __launch_bounds__(256) void attn_kernel(
    const float* __restrict__ QS1, const float* __restrict__ QS2,
    const float* __restrict__ Kbuf, const float* __restrict__ CONV,
    const float* __restrict__ Vbuf, float* __restrict__ AO)
{
    __shared__ float Qs[32][36];
    __shared__ float Ks[64][36];
    __shared__ float Vs[64][36];
    __shared__ float Ps[32][68];

    int q0 = blockIdx.x * 32;
    int h  = blockIdx.y;
    int b  = blockIdx.z;
    int tid = threadIdx.x;

    const float* Qbase;
    if (h < 4) Qbase = QS2 + (size_t)b * 1024 * 128 + h * 32;
    else       Qbase = QS1 + (size_t)b * 1024 * 128 + (h - 4) * 32;

    const float* Kb; int ldk;
    if (h >= 4)      { Kb = Kbuf + (size_t)b * 1024 * 256 + (h - 4) * 32; ldk = 256; }
    else if (h == 0) { Kb = CONV + (size_t)b * 1024 * 64 + 0;   ldk = 64; }
    else if (h == 1) { Kb = CONV + (size_t)b * 1024 * 64 + 32;  ldk = 64; }
    else if (h == 2) { Kb = Kbuf + (size_t)b * 1024 * 256 + 192; ldk = 256; }
    else             { Kb = Kbuf + (size_t)b * 1024 * 256 + 224; ldk = 256; }

    const float* Vb = Vbuf + (size_t)b * 1024 * 256 + h * 32;

    // load Q tile, fold in 1/sqrt(d)
    for (int i = tid; i < 32 * 32; i += 256) {
        int r = i >> 5, c = i & 31;
        Qs[r][c] = Qbase[(size_t)(q0 + r) * 128 + c] * 0.17677669529663687f;
    }

    int r = tid >> 3;
    int g = tid & 7;
    int d0 = g * 4;
    float acc0 = 0.f, acc1 = 0.f, acc2 = 0.f, acc3 = 0.f;
    float mrun = -1e30f, lrun = 0.f;

    for (int mt = 0; mt < 16; ++mt) {
        int m0 = mt * 64;
        for (int i = tid; i < 64 * 32; i += 256) {
            int kr = i >> 5, kc = i & 31;
            Ks[kr][kc] = Kb[(size_t)(m0 + kr) * ldk + kc];
            Vs[kr][kc] = Vb[(size_t)(m0 + kr) * 256 + kc];
        }
        __syncthreads();

        float s[8];
        float tmax = -1e30f;
        #pragma unroll
        for (int jj = 0; jj < 8; ++jj) {
            int m = g + jj * 8;
            float dot = 0.f;
            #pragma unroll
            for (int k = 0; k < 32; ++k) dot += Qs[r][k] * Ks[m][k];
            s[jj] = dot;
            tmax = fmaxf(tmax, dot);
        }
        tmax = fmaxf(tmax, __shfl_xor(tmax, 1));
        tmax = fmaxf(tmax, __shfl_xor(tmax, 2));
        tmax = fmaxf(tmax, __shfl_xor(tmax, 4));

        float mnew = fmaxf(mrun, tmax);
        float resc = __expf(mrun - mnew);
        float tsum = 0.f;
        #pragma unroll
        for (int jj = 0; jj < 8; ++jj) {
            float p = __expf(s[jj] - mnew);
            Ps[r][g + jj * 8] = p;
            tsum += p;
        }
        tsum += __shfl_xor(tsum, 1);
        tsum += __shfl_xor(tsum, 2);
        tsum += __shfl_xor(tsum, 4);
        lrun = lrun * resc + tsum;
        mrun = mnew;
        acc0 *= resc; acc1 *= resc; acc2 *= resc; acc3 *= resc;

        // P writes/reads stay within one 8-lane group (same wave) -> no barrier
        for (int m = 0; m < 64; ++m) {
            float p = Ps[r][m];
            float4 vv = *(const float4*)&Vs[m][d0];
            acc0 += p * vv.x; acc1 += p * vv.y; acc2 += p * vv.z; acc3 += p * vv.w;
        }
        __syncthreads();   // before overwriting Ks/Vs
    }

    float inv = 1.0f / lrun;
    float4 o;
    o.x = acc0 * inv; o.y = acc1 * inv; o.z = acc2 * inv; o.w = acc3 * inv;
    size_t obase = ((size_t)(b * 1024 + q0 + r)) * 256 + h * 32 + d0;
    *(float4*)&AO[obase] = o;
}

// ---------------------------------------------------------------------------
extern "C" void kernel_launch(void* const* d_in, const int* in_sizes, int n_in,
                              void* d_out, int out_size, void* d_ws, size_t ws_size,
                              hipStream_t stream)
{
    const float* src1 = (const float*)d_in[0];
    const float* src2 = (const float*)d_in[1];
    const float* Wq1  = (const float*)d_in[2];
    const float* bq1  = (const float*)d_in[3];
    const float* Wq2  = (const float*)d_in[4];
    const float* bq2  = (const float*)d_in[5];
    const float* Wk   = (const float*)d_in[6];
    const float* bk   = (const float*)d_in[7];
    const float* Wv   = (const float*)d_in[8];
    const float* bv   = (const float*)d_in[9];
    const float* cw   = (const float*)d_in[10];
    const float* cb   = (const float*)d_in[11];
    const float* Wo   = (const float*)d_in[12];
    const float* bo   = (const float*)d_in[13];
    float* out = (float*)d_out;

    float* ws  = (float*)d_ws;
    float* X1  = ws;                     // 4096*256
    float* X2  = X1  + 4096 * 256;       // 4096*256
    float* QS1 = X2  + 4096 * 256;       // 4096*128
    float* QS2 = QS1 + 4096 * 128;       // 4096*128
    float* Kb  = QS2 + 4096 * 128;       // 4096*256
    float* Vb  = Kb  + 4096 * 256;       // 4096*256
    float* CV  = Vb  + 4096 * 256;       // 4096*64
    float* AO  = CV  + 4096 * 64;        // 4096*256

    pe_add_kernel<<<1024, 256, 0, stream>>>(src1, src2, X1, X2);
    gemm64<1><<<dim3(2, 64), 256, 0, stream>>>(X1, Wq1, bq1, QS1, 128);
    gemm64<1><<<dim3(2, 64), 256, 0, stream>>>(X2, Wq2, bq2, QS2, 128);
    gemm64<0><<<dim3(4, 64), 256, 0, stream>>>(X1, Wk, bk, Kb, 256);
    gemm64<0><<<dim3(4, 64), 256, 0, stream>>>(X1, Wv, bv, Vb, 256);
    conv3x3_kernel<<<1024, 256, 0, stream>>>(Kb, cw, cb, CV);
    attn_kernel<<<dim3(32, 8, 4), 256, 0, stream>>>(QS1, QS2, Kb, CV, Vb, AO);
    gemm64<0><<<dim3(4, 64), 256, 0, stream>>>(AO, Wo, bo, out, 256);
}

// Round 2
// 135.286 us; speedup vs baseline: 1.4720x; 1.4720x over previous
//
#include <hip/hip_runtime.h>
#include <cstdint>
#include <cstddef>

typedef __attribute__((ext_vector_type(8))) short short8v;   // 8 bf16 in 4 VGPRs
typedef __attribute__((ext_vector_type(4))) float f32x4;

__device__ inline unsigned short f2bf(float x) {
    unsigned int u = __float_as_uint(x);
    unsigned int r = (u + 0x7FFFu + ((u >> 16) & 1u)) >> 16;   // RNE
    return (unsigned short)r;
}

// ---------------------------------------------------------------------------
// Kernel 1: X1 = src1 + pe, X2 = src2 + pe
// ---------------------------------------------------------------------------
__global__ __launch_bounds__(256) void pe_add_kernel(
    const float* __restrict__ src1, const float* __restrict__ src2,
    float* __restrict__ X1, float* __restrict__ X2)
{
    int n = blockIdx.x;      // 0..1023
    int c = threadIdx.x;     // 0..255
    int row = n >> 5, col = n & 31;
    float pos = (c < 128) ? (float)(row + 1) : (float)(col + 1);
    int cc = c & 63;
    float freq = expf(-0.14391156831212787f * (float)cc);
    float pe = sinf(pos * freq);
    for (int b = 0; b < 4; ++b) {
        size_t idx = ((size_t)b * 1024 + n) * 256 + c;
        X1[idx] = src1[idx] + pe;
        X2[idx] = src2[idx] + pe;
    }
}

// ---------------------------------------------------------------------------
// Kernel 2: fp32 GEMM  C = A(4096x256) @ W(256xNcols) + bias  (FOLD: head-sum)
// ---------------------------------------------------------------------------
template<int FOLD>
__global__ __launch_bounds__(256) void gemm64(
    const float* __restrict__ A, const float* __restrict__ W,
    const float* __restrict__ bias, float* __restrict__ C, int Ncols)
{
    __shared__ float As[64][68];
    __shared__ float Bs[64][68];
    int tx = threadIdx.x & 15, ty = threadIdx.x >> 4;
    int rowBase = blockIdx.y * 64;
    int colBase = blockIdx.x * 64;

    float acc[4][4] = {};

    for (int k0 = 0; k0 < 256; k0 += 64) {
        #pragma unroll
        for (int rr = 0; rr < 4; ++rr) {
            int r = ty + rr * 16;
            float4 av = *(const float4*)&A[(size_t)(rowBase + r) * 256 + k0 + tx * 4];
            *(float4*)&As[r][tx * 4] = av;
        }
        #pragma unroll
        for (int rr = 0; rr < 4; ++rr) {
            int kk = ty + rr * 16;
            float4 wv = *(const float4*)&W[(size_t)(k0 + kk) * 256 + colBase + tx * 4];
            if (FOLD) {
                float4 w2 = *(const float4*)&W[(size_t)(k0 + kk) * 256 + colBase + tx * 4 + 128];
                wv.x += w2.x; wv.y += w2.y; wv.z += w2.z; wv.w += w2.w;
            }
            *(float4*)&Bs[kk][tx * 4] = wv;
        }
        __syncthreads();
        #pragma unroll
        for (int kk = 0; kk < 64; ++kk) {
            float a0 = As[ty * 4 + 0][kk];
            float a1 = As[ty * 4 + 1][kk];
            float a2 = As[ty * 4 + 2][kk];
            float a3 = As[ty * 4 + 3][kk];
            float4 bv = *(const float4*)&Bs[kk][tx * 4];
            acc[0][0] += a0 * bv.x; acc[0][1] += a0 * bv.y; acc[0][2] += a0 * bv.z; acc[0][3] += a0 * bv.w;
            acc[1][0] += a1 * bv.x; acc[1][1] += a1 * bv.y; acc[1][2] += a1 * bv.z; acc[1][3] += a1 * bv.w;
            acc[2][0] += a2 * bv.x; acc[2][1] += a2 * bv.y; acc[2][2] += a2 * bv.z; acc[2][3] += a2 * bv.w;
            acc[3][0] += a3 * bv.x; acc[3][1] += a3 * bv.y; acc[3][2] += a3 * bv.z; acc[3][3] += a3 * bv.w;
        }
        __syncthreads();
    }

    #pragma unroll
    for (int i = 0; i < 4; ++i) {
        int r = rowBase + ty * 4 + i;
        float4 o;
        int cb = colBase + tx * 4;
        float b0 = bias[cb + 0], b1 = bias[cb + 1], b2 = bias[cb + 2], b3 = bias[cb + 3];
        if (FOLD) {
            b0 += bias[cb + 128]; b1 += bias[cb + 129]; b2 += bias[cb + 130]; b3 += bias[cb + 131];
        }
        o.x = acc[i][0] + b0; o.y = acc[i][1] + b1; o.z = acc[i][2] + b2; o.w = acc[i][3] + b3;
        *(float4*)&C[(size_t)r * Ncols + cb] = o;
    }
}

// ---------------------------------------------------------------------------
// Kernel 3: 3x3 SAME conv on K channels 128..191
// ---------------------------------------------------------------------------
__global__ __launch_bounds__(256) void conv3x3_kernel(
    const float* __restrict__ Kbuf, const float* __restrict__ cw,
    const float* __restrict__ cb, float* __restrict__ CONV)
{
    __shared__ float in_s[3][6][64];
    int blk = blockIdx.x;
    int b = blk >> 8;
    int ng = blk & 255;
    int n0 = ng * 4;
    int y = n0 >> 5;
    int x0 = n0 & 31;
    int tid = threadIdx.x;

    for (int idx = tid; idx < 3 * 6 * 64; idx += 256) {
        int ci = idx & 63;
        int rem = idx >> 6;
        int rx = rem % 6;
        int ry = rem / 6;
        int gy = y - 1 + ry;
        int gx = x0 - 1 + rx;
        float v = 0.f;
        if (gy >= 0 && gy < 32 && gx >= 0 && gx < 32)
            v = Kbuf[((size_t)(b * 1024 + gy * 32 + gx)) * 256 + 128 + ci];
        in_s[ry][rx][ci] = v;
    }
    __syncthreads();

    int px = tid >> 6;
    int co = tid & 63;
    float acc = cb[co];
    #pragma unroll
    for (int ky = 0; ky < 3; ++ky)
        #pragma unroll
        for (int kx = 0; kx < 3; ++kx)
            for (int ci = 0; ci < 64; ++ci)
                acc += in_s[ky][px + kx][ci] * cw[(((ky * 3 + kx) * 64 + ci) << 6) + co];

    CONV[((size_t)(b * 1024 + n0 + px)) << 6 | co] = acc;
}

// ---------------------------------------------------------------------------
// Kernel 4: pack per-head bf16 Q (scaled), K (head-mapped), V^T.
// grid (16 ntiles, 32 bh), 256 threads.
//   Qbf[bh][n][32], Kbf[bh][n][32], VTbf[bh][32][1024]
// ---------------------------------------------------------------------------
__global__ __launch_bounds__(256) void pack_kernel(
    const float* __restrict__ QS1, const float* __restrict__ QS2,
    const float* __restrict__ Kb, const float* __restrict__ CV,
    const float* __restrict__ Vb,
    unsigned short* __restrict__ Qbf, unsigned short* __restrict__ Kbf,
    unsigned short* __restrict__ VTbf)
{
    const float scale = 0.17677669529663687f;  // 1/sqrt(32)
    int bh = blockIdx.y;
    int b = bh >> 3, h = bh & 7;
    int n0 = blockIdx.x * 64;
    int t = threadIdx.x;

    // ---- Q and K: 8 channels per thread
    {
        int n = n0 + (t >> 2);
        int c0 = (t & 3) * 8;
        const float* qsrc = (h < 4)
            ? QS2 + ((size_t)(b * 1024 + n)) * 128 + h * 32
            : QS1 + ((size_t)(b * 1024 + n)) * 128 + (h - 4) * 32;
        const float* ksrc;
        if (h >= 4)      ksrc = Kb + ((size_t)(b * 1024 + n)) * 256 + (h - 4) * 32;
        else if (h == 0) ksrc = CV + ((size_t)(b * 1024 + n)) * 64;
        else if (h == 1) ksrc = CV + ((size_t)(b * 1024 + n)) * 64 + 32;
        else if (h == 2) ksrc = Kb + ((size_t)(b * 1024 + n)) * 256 + 192;
        else             ksrc = Kb + ((size_t)(b * 1024 + n)) * 256 + 224;

        unsigned short qo[8], ko[8];
        #pragma unroll
        for (int i = 0; i < 8; ++i) {
            qo[i] = f2bf(qsrc[c0 + i] * scale);
            ko[i] = f2bf(ksrc[c0 + i]);
        }
        *(short8v*)&Qbf[((size_t)bh * 1024 + n) * 32 + c0] = *(short8v*)qo;
        *(short8v*)&Kbf[((size_t)bh * 1024 + n) * 32 + c0] = *(short8v*)ko;
    }
    // ---- V^T: thread handles d = t>>3, 8 consecutive n
    {
        int d = t >> 3;
        int ns = (t & 7) * 8;
        unsigned short vo[8];
        #pragma unroll
        for (int i = 0; i < 8; ++i)
            vo[i] = f2bf(Vb[((size_t)(b * 1024 + n0 + ns + i)) * 256 + h * 32 + d]);
        *(short8v*)&VTbf[((size_t)bh * 32 + d) * 1024 + n0 + ns] = *(short8v*)vo;
    }
}

// ---------------------------------------------------------------------------
// Kernel 5: MFMA flash attention. Block = (64 q-rows, one bh). 4 waves,
// each wave owns 16 q-rows. KV tiles of 64. bf16 QK^T and PV, fp32 softmax.
// ---------------------------------------------------------------------------
__global__ __launch_bounds__(256) void attn_mfma_kernel(
    const unsigned short* __restrict__ Qbf, const unsigned short* __restrict__ Kbf,
    const unsigned short* __restrict__ VTbf, float* __restrict__ AO)
{
    __shared__ unsigned short Kt[64][32];     // [kpos][ch]
    __shared__ unsigned short VT[32][72];     // [d][kpos], padded
    __shared__ unsigned short Ps[4][16][72];  // per-wave P, padded

    int bh = blockIdx.y;
    int q0 = blockIdx.x * 64;
    int tid = threadIdx.x;
    int w = tid >> 6, l = tid & 63;
    int lr = l & 15, g = l >> 4;

    // Q A-fragment: row = q0 + w*16 + lr, k-chans g*8..g*8+7 (16B contiguous)
    short8v qfrag = *(const short8v*)&Qbf[((size_t)bh * 1024 + q0 + w * 16 + lr) * 32 + g * 8];

    f32x4 accO[2] = {};
    float mrow[4] = {-1e30f, -1e30f, -1e30f, -1e30f};
    float lrow[4] = {0.f, 0.f, 0.f, 0.f};
    const f32x4 zero = {};

    for (int mt = 0; mt < 16; ++mt) {
        int m0 = mt * 64;
        // stage K tile: 4KB, 256 threads x 16B, linear
        ((short8v*)&Kt[0][0])[tid] =
            *(const short8v*)&Kbf[((size_t)bh * 1024 + m0) * 32 + tid * 8];
        // stage V^T tile: 32 rows x 64 cols
        *(short8v*)&VT[tid >> 3][(tid & 7) * 8] =
            *(const short8v*)&VTbf[((size_t)bh * 32 + (tid >> 3)) * 1024 + m0 + (tid & 7) * 8];
        __syncthreads();

        // QK^T: S(16 q x 64 k) = 4 MFMAs
        f32x4 s[4];
        #pragma unroll
        for (int t = 0; t < 4; ++t) {
            short8v kf = *(const short8v*)&Kt[t * 16 + lr][g * 8];
            s[t] = __builtin_amdgcn_mfma_f32_16x16x32_bf16(qfrag, kf, zero, 0, 0, 0);
        }

        // online softmax; C-layout row = g*4 + r, col = t*16 + lr
        float resc[4];
        #pragma unroll
        for (int r = 0; r < 4; ++r) {
            float tm = fmaxf(fmaxf(s[0][r], s[1][r]), fmaxf(s[2][r], s[3][r]));
            tm = fmaxf(tm, __shfl_xor(tm, 1));
            tm = fmaxf(tm, __shfl_xor(tm, 2));
            tm = fmaxf(tm, __shfl_xor(tm, 4));
            tm = fmaxf(tm, __shfl_xor(tm, 8));
            float mnew = fmaxf(mrow[r], tm);
            resc[r] = __expf(mrow[r] - mnew);
            float ts = 0.f;
            #pragma unroll
            for (int t = 0; t < 4; ++t) {
                float p = __expf(s[t][r] - mnew);
                s[t][r] = p;
                ts += p;
            }
            ts += __shfl_xor(ts, 1);
            ts += __shfl_xor(ts, 2);
            ts += __shfl_xor(ts, 4);
            ts += __shfl_xor(ts, 8);
            lrow[r] = lrow[r] * resc[r] + ts;
            mrow[r] = mnew;
        }

        // write P (bf16) to per-wave LDS
        #pragma unroll
        for (int r = 0; r < 4; ++r)
            #pragma unroll
            for (int t = 0; t < 4; ++t)
                Ps[w][g * 4 + r][t * 16 + lr] = f2bf(s[t][r]);

        // rescale O accumulators
        #pragma unroll
        for (int nt = 0; nt < 2; ++nt)
            #pragma unroll
            for (int r = 0; r < 4; ++r)
                accO[nt][r] *= resc[r];

        // PV: O(16 x 32) += P(16 x 64) @ V(64 x 32); 4 MFMAs
        #pragma unroll
        for (int kt = 0; kt < 2; ++kt) {
            short8v pa = *(const short8v*)&Ps[w][lr][kt * 32 + g * 8];
            #pragma unroll
            for (int nt = 0; nt < 2; ++nt) {
                short8v vb = *(const short8v*)&VT[nt * 16 + lr][kt * 32 + g * 8];
                accO[nt] = __builtin_amdgcn_mfma_f32_16x16x32_bf16(pa, vb, accO[nt], 0, 0, 0);
            }
        }
        __syncthreads();
    }

    // epilogue: divide by softmax denom, write AO[b][q][h*32 + d]
    float inv[4];
    #pragma unroll
    for (int r = 0; r < 4; ++r) inv[r] = 1.0f / lrow[r];
    int b = bh >> 3, h = bh & 7;
    #pragma unroll
    for (int nt = 0; nt < 2; ++nt)
        #pragma unroll
        for (int r = 0; r < 4; ++r) {
            int q = q0 + w * 16 + g * 4 + r;
            AO[((size_t)(b * 1024 + q)) * 256 + h * 32 + nt * 16 + lr] = accO[nt][r] * inv[r];
        }
}

// ---------------------------------------------------------------------------
extern "C" void kernel_launch(void* const* d_in, const int* in_sizes, int n_in,
                              void* d_out, int out_size, void* d_ws, size_t ws_size,
                              hipStream_t stream)
{
    const float* src1 = (const float*)d_in[0];
    const float* src2 = (const float*)d_in[1];
    const float* Wq1  = (const float*)d_in[2];
    const float* bq1  = (const float*)d_in[3];
    const float* Wq2  = (const float*)d_in[4];
    const float* bq2  = (const float*)d_in[5];
    const float* Wk   = (const float*)d_in[6];
    const float* bk   = (const float*)d_in[7];
    const float* Wv   = (const float*)d_in[8];
    const float* bv   = (const float*)d_in[9];
    const float* cw   = (const float*)d_in[10];
    const float* cb   = (const float*)d_in[11];
    const float* Wo   = (const float*)d_in[12];
    const float* bo   = (const float*)d_in[13];
    float* out = (float*)d_out;

    char* base = (char*)d_ws;
    float* X1  = (float*)(base + 0);            // 4 MB
    float* X2  = (float*)(base + (4u  << 20));  // 4 MB
    float* QS1 = (float*)(base + (8u  << 20));  // 2 MB
    float* QS2 = (float*)(base + (10u << 20));  // 2 MB
    float* Kb  = (float*)(base + (12u << 20));  // 4 MB
    float* Vb  = (float*)(base + (16u << 20));  // 4 MB
    float* CV  = (float*)(base + (20u << 20));  // 1 MB
    float* AO  = (float*)(base + (21u << 20));  // 4 MB
    unsigned short* Qbf  = (unsigned short*)(base + (25u << 20)); // 2 MB
    unsigned short* Kbf  = (unsigned short*)(base + (27u << 20)); // 2 MB
    unsigned short* VTbf = (unsigned short*)(base + (29u << 20)); // 2 MB

    pe_add_kernel<<<1024, 256, 0, stream>>>(src1, src2, X1, X2);
    gemm64<1><<<dim3(2, 64), 256, 0, stream>>>(X1, Wq1, bq1, QS1, 128);
    gemm64<1><<<dim3(2, 64), 256, 0, stream>>>(X2, Wq2, bq2, QS2, 128);
    gemm64<0><<<dim3(4, 64), 256, 0, stream>>>(X1, Wk, bk, Kb, 256);
    gemm64<0><<<dim3(4, 64), 256, 0, stream>>>(X1, Wv, bv, Vb, 256);
    conv3x3_kernel<<<1024, 256, 0, stream>>>(Kb, cw, cb, CV);
    pack_kernel<<<dim3(16, 32), 256, 0, stream>>>(QS1, QS2, Kb, CV, Vb, Qbf, Kbf, VTbf);
    attn_mfma_kernel<<<dim3(16, 32), 256, 0, stream>>>(Qbf, Kbf, VTbf, AO);
    gemm64<0><<<dim3(4, 64), 256, 0, stream>>>(AO, Wo, bo, out, 256);
}

// Round 3
// 81.458 us; speedup vs baseline: 2.4448x; 1.6608x over previous
//
#include <hip/hip_runtime.h>
#include <cstdint>
#include <cstddef>

typedef __attribute__((ext_vector_type(8))) short short8v;   // 8 bf16 = 4 VGPRs
typedef __attribute__((ext_vector_type(4))) short short4v;   // 4 bf16 = 8B
typedef __attribute__((ext_vector_type(4))) float f32x4;
typedef unsigned short ushort_t;

__device__ inline unsigned short f2bf(float x) {
    unsigned int u = __float_as_uint(x);
    return (unsigned short)((u + 0x7FFFu + ((u >> 16) & 1u)) >> 16);   // RNE
}

// ---------------------------------------------------------------------------
// Kernel 1: X1 = bf16(src1 + pe), X2 = bf16(src2 + pe)
// ---------------------------------------------------------------------------
__global__ __launch_bounds__(256) void pe_add_bf16(
    const float* __restrict__ src1, const float* __restrict__ src2,
    ushort_t* __restrict__ X1, ushort_t* __restrict__ X2)
{
    int n = blockIdx.x, c = threadIdx.x;
    int row = n >> 5, col = n & 31;
    float pos = (c < 128) ? (float)(row + 1) : (float)(col + 1);
    float freq = expf(-0.14391156831212787f * (float)(c & 63));
    float pe = sinf(pos * freq);
    for (int b = 0; b < 4; ++b) {
        size_t idx = ((size_t)b * 1024 + n) * 256 + c;
        X1[idx] = f2bf(src1[idx] + pe);
        X2[idx] = f2bf(src2[idx] + pe);
    }
}

// ---------------------------------------------------------------------------
// Kernel 2: weight prep — transpose to [col][k] bf16, fold Wq halves, fold bq.
// grid (4,4,5): (k-tile, c-tile, matrix). fold matrices have only c-tiles 0,1.
// ---------------------------------------------------------------------------
__global__ __launch_bounds__(256) void prep_weights(
    const float* __restrict__ Wq1, const float* __restrict__ Wq2,
    const float* __restrict__ Wk, const float* __restrict__ Wv,
    const float* __restrict__ Wo,
    const float* __restrict__ bq1, const float* __restrict__ bq2,
    ushort_t* __restrict__ WqT1, ushort_t* __restrict__ WqT2,
    ushort_t* __restrict__ WkT, ushort_t* __restrict__ WvT,
    ushort_t* __restrict__ WoT, float* __restrict__ bq1f, float* __restrict__ bq2f)
{
    __shared__ ushort_t Ts[64][72];
    int m = blockIdx.z;
    int k0 = blockIdx.x * 64, c0 = blockIdx.y * 64;
    const float* W; ushort_t* WT; int fold = 0;
    switch (m) {
        case 0: W = Wq1; WT = WqT1; fold = 1; break;
        case 1: W = Wq2; WT = WqT2; fold = 1; break;
        case 2: W = Wk;  WT = WkT;  break;
        case 3: W = Wv;  WT = WvT;  break;
        default: W = Wo; WT = WoT;  break;
    }
    int t = threadIdx.x;
    if (m == 0 && blockIdx.x == 0 && blockIdx.y == 0 && t < 128) bq1f[t] = bq1[t] + bq1[t + 128];
    if (m == 1 && blockIdx.x == 0 && blockIdx.y == 0 && t < 128) bq2f[t] = bq2[t] + bq2[t + 128];
    if (fold && c0 >= 128) return;   // block-uniform exit

    int kr = t >> 2, cq = t & 3;
    #pragma unroll
    for (int i = 0; i < 4; ++i) {
        int cc = cq * 16 + i * 4;
        float4 v = *(const float4*)&W[(size_t)(k0 + kr) * 256 + c0 + cc];
        if (fold) {
            float4 v2 = *(const float4*)&W[(size_t)(k0 + kr) * 256 + c0 + cc + 128];
            v.x += v2.x; v.y += v2.y; v.z += v2.z; v.w += v2.w;
        }
        Ts[kr][cc + 0] = f2bf(v.x); Ts[kr][cc + 1] = f2bf(v.y);
        Ts[kr][cc + 2] = f2bf(v.z); Ts[kr][cc + 3] = f2bf(v.w);
    }
    __syncthreads();
    int cr = t >> 2, kq = t & 3;
    ushort_t tmp[16];
    #pragma unroll
    for (int i = 0; i < 16; ++i) tmp[i] = Ts[kq * 16 + i][cr];
    *(short8v*)&WT[(size_t)(c0 + cr) * 256 + k0 + kq * 16]     = *(short8v*)&tmp[0];
    *(short8v*)&WT[(size_t)(c0 + cr) * 256 + k0 + kq * 16 + 8] = *(short8v*)&tmp[8];
}

// ---------------------------------------------------------------------------
// Kernel 3: bf16 MFMA GEMM, 64x64 tile, BK=128, 4 waves (2x2 of 32x32).
//  A[4096][256] bf16, BT[N][256] bf16 (pre-transposed), bias fp32.
//  MODE 0: Q-proj -> Qbf[(b*8+hofs+c/32)][n][c%32], value (acc+bias)*scale
//  MODE 1: K-proj -> Kbf heads (c<128 -> 4+c/32; c>=192 -> 2+(c-192)/32),
//          cols 128..191 -> CVin fp32 [n][c-128] (conv input)
//  MODE 2: V-proj -> VTbf[(b*8+c/32)*32 + c%32][n]  (transposed, vector store)
//  MODE 3: O-proj -> out fp32 [n][c]
// ---------------------------------------------------------------------------
template<int MODE>
__global__ __launch_bounds__(256) void gemm_bf16(
    const ushort_t* __restrict__ A, const ushort_t* __restrict__ BT,
    const float* __restrict__ bias, void* __restrict__ out0,
    void* __restrict__ out1, int hofs)
{
    __shared__ ushort_t As[64][136];
    __shared__ ushort_t Bs[64][136];
    int rowBase = blockIdx.y * 64, colBase = blockIdx.x * 64;
    int tid = threadIdx.x;
    int w = tid >> 6, l = tid & 63, lr = l & 15, g = l >> 4;
    int wr = w >> 1, wc = w & 1;
    int tr = tid >> 2, tq = tid & 3;
    f32x4 acc[2][2] = {};

    for (int kb = 0; kb < 256; kb += 128) {
        #pragma unroll
        for (int i = 0; i < 4; ++i)
            *(short8v*)&As[tr][tq * 32 + i * 8] =
                *(const short8v*)&A[(size_t)(rowBase + tr) * 256 + kb + tq * 32 + i * 8];
        #pragma unroll
        for (int i = 0; i < 4; ++i)
            *(short8v*)&Bs[tr][tq * 32 + i * 8] =
                *(const short8v*)&BT[(size_t)(colBase + tr) * 256 + kb + tq * 32 + i * 8];
        __syncthreads();
        #pragma unroll
        for (int ks = 0; ks < 4; ++ks) {
            short8v a0 = *(const short8v*)&As[wr * 32 + lr][ks * 32 + g * 8];
            short8v a1 = *(const short8v*)&As[wr * 32 + 16 + lr][ks * 32 + g * 8];
            short8v b0 = *(const short8v*)&Bs[wc * 32 + lr][ks * 32 + g * 8];
            short8v b1 = *(const short8v*)&Bs[wc * 32 + 16 + lr][ks * 32 + g * 8];
            acc[0][0] = __builtin_amdgcn_mfma_f32_16x16x32_bf16(a0, b0, acc[0][0], 0, 0, 0);
            acc[0][1] = __builtin_amdgcn_mfma_f32_16x16x32_bf16(a0, b1, acc[0][1], 0, 0, 0);
            acc[1][0] = __builtin_amdgcn_mfma_f32_16x16x32_bf16(a1, b0, acc[1][0], 0, 0, 0);
            acc[1][1] = __builtin_amdgcn_mfma_f32_16x16x32_bf16(a1, b1, acc[1][1], 0, 0, 0);
        }
        __syncthreads();
    }

    #pragma unroll
    for (int fr = 0; fr < 2; ++fr)
        #pragma unroll
        for (int fc = 0; fc < 2; ++fc) {
            int c = colBase + wc * 32 + fc * 16 + lr;
            float bv = bias[c];
            int nb = rowBase + wr * 32 + fr * 16 + g * 4;
            if (MODE == 2) {
                int b = nb >> 10, h = c >> 5, d = c & 31;
                short4v pk;
                #pragma unroll
                for (int r = 0; r < 4; ++r) pk[r] = (short)f2bf(acc[fr][fc][r] + bv);
                *(short4v*)&((ushort_t*)out0)[((size_t)((b * 8 + h) * 32 + d)) * 1024 + (nb & 1023)] = pk;
            } else {
                #pragma unroll
                for (int r = 0; r < 4; ++r) {
                    int n = nb + r;
                    float v = acc[fr][fc][r] + bv;
                    if (MODE == 0) {
                        int b = n >> 10, h = hofs + (c >> 5), d = c & 31;
                        ((ushort_t*)out0)[(((size_t)(b * 8 + h) << 10) | (n & 1023)) * 32 + d] =
                            f2bf(v * 0.17677669529663687f);
                    } else if (MODE == 1) {
                        int b = n >> 10;
                        if (c < 128) {
                            int h = 4 + (c >> 5), d = c & 31;
                            ((ushort_t*)out0)[(((size_t)(b * 8 + h) << 10) | (n & 1023)) * 32 + d] = f2bf(v);
                        } else if (c < 192) {
                            ((float*)out1)[(size_t)n * 64 + (c - 128)] = v;
                        } else {
                            int h = 2 + ((c - 192) >> 5), d = c & 31;
                            ((ushort_t*)out0)[(((size_t)(b * 8 + h) << 10) | (n & 1023)) * 32 + d] = f2bf(v);
                        }
                    } else {   // MODE 3
                        ((float*)out0)[(size_t)n * 256 + c] = v;
                    }
                }
            }
        }
}

// ---------------------------------------------------------------------------
// Kernel 4: 3x3 SAME conv, input CVin fp32 [4096][64], output -> Kbf heads 0,1
// ---------------------------------------------------------------------------
__global__ __launch_bounds__(256) void conv3x3_kernel(
    const float* __restrict__ CVin, const float* __restrict__ cw,
    const float* __restrict__ cb, ushort_t* __restrict__ Kbf)
{
    __shared__ float in_s[3][6][64];
    int blk = blockIdx.x;
    int b = blk >> 8, ng = blk & 255;
    int n0 = ng * 4, y = n0 >> 5, x0 = n0 & 31;
    int tid = threadIdx.x;

    for (int idx = tid; idx < 3 * 6 * 64; idx += 256) {
        int ci = idx & 63, rem = idx >> 6, rx = rem % 6, ry = rem / 6;
        int gy = y - 1 + ry, gx = x0 - 1 + rx;
        float v = 0.f;
        if (gy >= 0 && gy < 32 && gx >= 0 && gx < 32)
            v = CVin[((size_t)(b * 1024 + gy * 32 + gx)) * 64 + ci];
        in_s[ry][rx][ci] = v;
    }
    __syncthreads();

    int px = tid >> 6, co = tid & 63;
    float acc = cb[co];
    #pragma unroll
    for (int ky = 0; ky < 3; ++ky)
        #pragma unroll
        for (int kx = 0; kx < 3; ++kx)
            #pragma unroll 8
            for (int ci = 0; ci < 64; ++ci)
                acc += in_s[ky][px + kx][ci] * cw[(((ky * 3 + kx) * 64 + ci) << 6) + co];

    int h = co >> 5, d = co & 31;
    int n = n0 + px;
    Kbf[(((size_t)(b * 8 + h) << 10) | n) * 32 + d] = f2bf(acc);
}

// ---------------------------------------------------------------------------
// Kernel 5: MFMA flash attention, swapped QK^T, no-max softmax.
// Block = (64 q-rows, one bh), 4 waves x 16 q-rows. KV tiles of 64.
//  S^T = mfma(Kfrag, Qfrag): lane holds P[q=lane&15][k = 16t + 4g + r]
//  -> 4x ds_write_b64 into Ps[q][k] (contiguous), A-frag read is b128.
//  l = deferred per-lane partial, reduced once at the end (no max, no rescale).
// ---------------------------------------------------------------------------
__global__ __launch_bounds__(256) void attn_mfma2(
    const ushort_t* __restrict__ Qbf, const ushort_t* __restrict__ Kbf,
    const ushort_t* __restrict__ VTbf, ushort_t* __restrict__ AObf)
{
    __shared__ ushort_t Kt[64][32];
    __shared__ ushort_t VT[32][72];
    __shared__ ushort_t Ps[4][16][72];

    int bh = blockIdx.y, q0 = blockIdx.x * 64;
    int tid = threadIdx.x, w = tid >> 6, l = tid & 63, lr = l & 15, g = l >> 4;

    short8v qfrag = *(const short8v*)&Qbf[((size_t)bh * 1024 + q0 + w * 16 + lr) * 32 + g * 8];

    f32x4 accO[2] = {};
    float lsum = 0.f;
    const f32x4 zero = {};

    for (int mt = 0; mt < 16; ++mt) {
        int m0 = mt * 64;
        ((short8v*)&Kt[0][0])[tid] =
            *(const short8v*)&Kbf[((size_t)bh * 1024 + m0) * 32 + tid * 8];
        *(short8v*)&VT[tid >> 3][(tid & 7) * 8] =
            *(const short8v*)&VTbf[((size_t)bh * 32 + (tid >> 3)) * 1024 + m0 + (tid & 7) * 8];
        __syncthreads();

        // swapped QK^T: S^T tile, lane holds q=lr, kpos = 16t + 4g + r
        f32x4 st[4];
        #pragma unroll
        for (int t = 0; t < 4; ++t) {
            short8v kf = *(const short8v*)&Kt[t * 16 + lr][g * 8];
            st[t] = __builtin_amdgcn_mfma_f32_16x16x32_bf16(kf, qfrag, zero, 0, 0, 0);
        }

        // exp (no max), deferred l partial, vectorized P write (4 bf16 = b64)
        #pragma unroll
        for (int t = 0; t < 4; ++t) {
            float p0 = __expf(st[t][0]), p1 = __expf(st[t][1]);
            float p2 = __expf(st[t][2]), p3 = __expf(st[t][3]);
            lsum += (p0 + p1) + (p2 + p3);
            short4v pw;
            pw[0] = (short)f2bf(p0); pw[1] = (short)f2bf(p1);
            pw[2] = (short)f2bf(p2); pw[3] = (short)f2bf(p3);
            *(short4v*)&Ps[w][lr][t * 16 + g * 4] = pw;
        }

        // PV: O(16x32) += P(16x64) @ V(64x32)
        #pragma unroll
        for (int kt = 0; kt < 2; ++kt) {
            short8v pa = *(const short8v*)&Ps[w][lr][kt * 32 + g * 8];
            #pragma unroll
            for (int nt = 0; nt < 2; ++nt) {
                short8v vb = *(const short8v*)&VT[nt * 16 + lr][kt * 32 + g * 8];
                accO[nt] = __builtin_amdgcn_mfma_f32_16x16x32_bf16(pa, vb, accO[nt], 0, 0, 0);
            }
        }
        __syncthreads();
    }

    // reduce l across the 4 g-groups (lanes sharing q = lr)
    lsum += __shfl_xor(lsum, 16);
    lsum += __shfl_xor(lsum, 32);

    int b = bh >> 3, h = bh & 7;
    #pragma unroll
    for (int r = 0; r < 4; ++r) {
        float lv = __uint_as_float((unsigned)__builtin_amdgcn_ds_bpermute(
            (g * 4 + r) * 4, (int)__float_as_uint(lsum)));
        float inv = 1.0f / lv;
        int n = q0 + w * 16 + g * 4 + r;
        #pragma unroll
        for (int nt = 0; nt < 2; ++nt)
            AObf[((size_t)(b * 1024 + n)) * 256 + h * 32 + nt * 16 + lr] =
                f2bf(accO[nt][r] * inv);
    }
}

// ---------------------------------------------------------------------------
extern "C" void kernel_launch(void* const* d_in, const int* in_sizes, int n_in,
                              void* d_out, int out_size, void* d_ws, size_t ws_size,
                              hipStream_t stream)
{
    const float* src1 = (const float*)d_in[0];
    const float* src2 = (const float*)d_in[1];
    const float* Wq1  = (const float*)d_in[2];
    const float* bq1  = (const float*)d_in[3];
    const float* Wq2  = (const float*)d_in[4];
    const float* bq2  = (const float*)d_in[5];
    const float* Wk   = (const float*)d_in[6];
    const float* bk   = (const float*)d_in[7];
    const float* Wv   = (const float*)d_in[8];
    const float* bv   = (const float*)d_in[9];
    const float* cw   = (const float*)d_in[10];
    const float* cb   = (const float*)d_in[11];
    const float* Wo   = (const float*)d_in[12];
    const float* bo   = (const float*)d_in[13];
    float* out = (float*)d_out;

    char* base = (char*)d_ws;
    const size_t MB = 1u << 20;
    ushort_t* X1bf = (ushort_t*)(base + 0 * MB);     // 2 MB
    ushort_t* X2bf = (ushort_t*)(base + 2 * MB);     // 2 MB
    ushort_t* Qbf  = (ushort_t*)(base + 4 * MB);     // 2 MB  [32 bh][1024][32]
    ushort_t* Kbf  = (ushort_t*)(base + 6 * MB);     // 2 MB  [32 bh][1024][32]
    ushort_t* VTbf = (ushort_t*)(base + 8 * MB);     // 2 MB  [32 bh][32][1024]
    ushort_t* AObf = (ushort_t*)(base + 10 * MB);    // 2 MB  [4096][256]
    float*    CVin = (float*)(base + 12 * MB);       // 1 MB  [4096][64]
    ushort_t* WqT1 = (ushort_t*)(base + 13 * MB);
    ushort_t* WqT2 = (ushort_t*)(base + 13 * MB + 128 * 1024);
    ushort_t* WkT  = (ushort_t*)(base + 13 * MB + 256 * 1024);
    ushort_t* WvT  = (ushort_t*)(base + 13 * MB + 384 * 1024);
    ushort_t* WoT  = (ushort_t*)(base + 13 * MB + 512 * 1024);
    float*    bq1f = (float*)(base + 13 * MB + 640 * 1024);
    float*    bq2f = (float*)(base + 13 * MB + 644 * 1024);

    pe_add_bf16<<<1024, 256, 0, stream>>>(src1, src2, X1bf, X2bf);
    prep_weights<<<dim3(4, 4, 5), 256, 0, stream>>>(
        Wq1, Wq2, Wk, Wv, Wo, bq1, bq2, WqT1, WqT2, WkT, WvT, WoT, bq1f, bq2f);
    gemm_bf16<0><<<dim3(2, 64), 256, 0, stream>>>(X1bf, WqT1, bq1f, Qbf, nullptr, 4);
    gemm_bf16<0><<<dim3(2, 64), 256, 0, stream>>>(X2bf, WqT2, bq2f, Qbf, nullptr, 0);
    gemm_bf16<1><<<dim3(4, 64), 256, 0, stream>>>(X1bf, WkT, bk, Kbf, CVin, 0);
    gemm_bf16<2><<<dim3(4, 64), 256, 0, stream>>>(X1bf, WvT, bv, VTbf, nullptr, 0);
    conv3x3_kernel<<<1024, 256, 0, stream>>>(CVin, cw, cb, Kbf);
    attn_mfma2<<<dim3(16, 32), 256, 0, stream>>>(Qbf, Kbf, VTbf, AObf);
    gemm_bf16<3><<<dim3(4, 64), 256, 0, stream>>>(AObf, WoT, bo, out, nullptr, 0);
}

// Round 4
// 70.016 us; speedup vs baseline: 2.8443x; 1.1634x over previous
//
#include <hip/hip_runtime.h>
#include <cstdint>
#include <cstddef>

typedef __attribute__((ext_vector_type(8))) short short8v;   // 8 bf16 = 4 VGPRs
typedef __attribute__((ext_vector_type(4))) short short4v;   // 4 bf16 = 8B
typedef __attribute__((ext_vector_type(4))) float f32x4;
typedef unsigned short ushort_t;

__device__ inline unsigned short f2bf(float x) {
    unsigned int u = __float_as_uint(x);
    return (unsigned short)((u + 0x7FFFu + ((u >> 16) & 1u)) >> 16);   // RNE
}

// ---------------------------------------------------------------------------
// Kernel 1: X1 = bf16(src1 + pe), X2 = bf16(src2 + pe)
// ---------------------------------------------------------------------------
__global__ __launch_bounds__(256) void pe_add_bf16(
    const float* __restrict__ src1, const float* __restrict__ src2,
    ushort_t* __restrict__ X1, ushort_t* __restrict__ X2)
{
    int n = blockIdx.x, c = threadIdx.x;
    int row = n >> 5, col = n & 31;
    float pos = (c < 128) ? (float)(row + 1) : (float)(col + 1);
    float freq = expf(-0.14391156831212787f * (float)(c & 63));
    float pe = sinf(pos * freq);
    for (int b = 0; b < 4; ++b) {
        size_t idx = ((size_t)b * 1024 + n) * 256 + c;
        X1[idx] = f2bf(src1[idx] + pe);
        X2[idx] = f2bf(src2[idx] + pe);
    }
}

// ---------------------------------------------------------------------------
// Kernel 2: weight prep.
// WcatT[768][256] bf16 rows = output cols: [0,128)=fold(Wq1), [128,256)=fold(Wq2),
// [256,512)=Wk, [512,768)=Wv. WoT[256][256]. bcat[768] biases (q folded).
// grid (4 ktiles, 16 ctiles).
// ---------------------------------------------------------------------------
__global__ __launch_bounds__(256) void prep_weights(
    const float* __restrict__ Wq1, const float* __restrict__ Wq2,
    const float* __restrict__ Wk, const float* __restrict__ Wv,
    const float* __restrict__ Wo,
    const float* __restrict__ bq1, const float* __restrict__ bq2,
    const float* __restrict__ bk, const float* __restrict__ bv,
    ushort_t* __restrict__ WcatT, ushort_t* __restrict__ WoT,
    float* __restrict__ bcat)
{
    __shared__ ushort_t Ts[64][72];
    int kt = blockIdx.x, ct = blockIdx.y;
    int k0 = kt * 64;
    const float* W; int csrc; int fold = 0; ushort_t* dst; int dstbase;
    if (ct < 2)       { W = Wq1; csrc = ct * 64;        fold = 1; dst = WcatT; dstbase = ct * 64; }
    else if (ct < 4)  { W = Wq2; csrc = (ct - 2) * 64;  fold = 1; dst = WcatT; dstbase = ct * 64; }
    else if (ct < 8)  { W = Wk;  csrc = (ct - 4) * 64;            dst = WcatT; dstbase = ct * 64; }
    else if (ct < 12) { W = Wv;  csrc = (ct - 8) * 64;            dst = WcatT; dstbase = ct * 64; }
    else              { W = Wo;  csrc = (ct - 12) * 64;           dst = WoT;   dstbase = (ct - 12) * 64; }
    int t = threadIdx.x;
    if (kt == 0) {
        if (ct == 0 && t < 128) bcat[t] = bq1[t] + bq1[t + 128];
        if (ct == 2 && t < 128) bcat[128 + t] = bq2[t] + bq2[t + 128];
        if (ct == 4) bcat[256 + t] = bk[t];
        if (ct == 8) bcat[512 + t] = bv[t];
    }

    int kr = t >> 2, cq = t & 3;
    #pragma unroll
    for (int i = 0; i < 4; ++i) {
        int cc = cq * 16 + i * 4;
        float4 v = *(const float4*)&W[(size_t)(k0 + kr) * 256 + csrc + cc];
        if (fold) {
            float4 v2 = *(const float4*)&W[(size_t)(k0 + kr) * 256 + csrc + cc + 128];
            v.x += v2.x; v.y += v2.y; v.z += v2.z; v.w += v2.w;
        }
        Ts[kr][cc + 0] = f2bf(v.x); Ts[kr][cc + 1] = f2bf(v.y);
        Ts[kr][cc + 2] = f2bf(v.z); Ts[kr][cc + 3] = f2bf(v.w);
    }
    __syncthreads();
    int cr = t >> 2, kq = t & 3;
    ushort_t tmp[16];
    #pragma unroll
    for (int i = 0; i < 16; ++i) tmp[i] = Ts[kq * 16 + i][cr];
    *(short8v*)&dst[(size_t)(dstbase + cr) * 256 + k0 + kq * 16]     = *(short8v*)&tmp[0];
    *(short8v*)&dst[(size_t)(dstbase + cr) * 256 + k0 + kq * 16 + 8] = *(short8v*)&tmp[8];
}

// ---------------------------------------------------------------------------
// Kernel 3: merged projection GEMM. grid (12, 64); 64x64 tile, BK=128, 4 waves.
// A = X2 for col-tiles [2,4), else X1. Epilogue scatters by col range.
// ---------------------------------------------------------------------------
__global__ __launch_bounds__(256) void proj_gemm(
    const ushort_t* __restrict__ X1, const ushort_t* __restrict__ X2,
    const ushort_t* __restrict__ WcatT, const float* __restrict__ bcat,
    ushort_t* __restrict__ Qbf, ushort_t* __restrict__ Kbf,
    ushort_t* __restrict__ VTbf, float* __restrict__ CVin)
{
    __shared__ ushort_t As[64][136];
    __shared__ ushort_t Bs[64][136];
    int colBase = blockIdx.x * 64, rowBase = blockIdx.y * 64;
    const ushort_t* A = (colBase >= 128 && colBase < 256) ? X2 : X1;
    int tid = threadIdx.x;
    int w = tid >> 6, l = tid & 63, lr = l & 15, g = l >> 4;
    int wr = w >> 1, wc = w & 1;
    int tr = tid >> 2, tq = tid & 3;
    f32x4 acc[2][2] = {};

    for (int kb = 0; kb < 256; kb += 128) {
        #pragma unroll
        for (int i = 0; i < 4; ++i)
            *(short8v*)&As[tr][tq * 32 + i * 8] =
                *(const short8v*)&A[(size_t)(rowBase + tr) * 256 + kb + tq * 32 + i * 8];
        #pragma unroll
        for (int i = 0; i < 4; ++i)
            *(short8v*)&Bs[tr][tq * 32 + i * 8] =
                *(const short8v*)&WcatT[(size_t)(colBase + tr) * 256 + kb + tq * 32 + i * 8];
        __syncthreads();
        #pragma unroll
        for (int ks = 0; ks < 4; ++ks) {
            short8v a0 = *(const short8v*)&As[wr * 32 + lr][ks * 32 + g * 8];
            short8v a1 = *(const short8v*)&As[wr * 32 + 16 + lr][ks * 32 + g * 8];
            short8v b0 = *(const short8v*)&Bs[wc * 32 + lr][ks * 32 + g * 8];
            short8v b1 = *(const short8v*)&Bs[wc * 32 + 16 + lr][ks * 32 + g * 8];
            acc[0][0] = __builtin_amdgcn_mfma_f32_16x16x32_bf16(a0, b0, acc[0][0], 0, 0, 0);
            acc[0][1] = __builtin_amdgcn_mfma_f32_16x16x32_bf16(a0, b1, acc[0][1], 0, 0, 0);
            acc[1][0] = __builtin_amdgcn_mfma_f32_16x16x32_bf16(a1, b0, acc[1][0], 0, 0, 0);
            acc[1][1] = __builtin_amdgcn_mfma_f32_16x16x32_bf16(a1, b1, acc[1][1], 0, 0, 0);
        }
        __syncthreads();
    }

    const float scale = 0.17677669529663687f;
    #pragma unroll
    for (int fr = 0; fr < 2; ++fr)
        #pragma unroll
        for (int fc = 0; fc < 2; ++fc) {
            int c = colBase + wc * 32 + fc * 16 + lr;
            float bv = bcat[c];
            int nb = rowBase + wr * 32 + fr * 16 + g * 4;
            int b = nb >> 10;
            if (c < 512) {
                #pragma unroll
                for (int r = 0; r < 4; ++r) {
                    int n = nb + r;
                    float v = acc[fr][fc][r] + bv;
                    if (c < 128) {
                        int h = 4 + (c >> 5), d = c & 31;
                        Qbf[(((size_t)(b * 8 + h) << 10) | (n & 1023)) * 32 + d] = f2bf(v * scale);
                    } else if (c < 256) {
                        int c2 = c - 128;
                        int h = c2 >> 5, d = c2 & 31;
                        Qbf[(((size_t)(b * 8 + h) << 10) | (n & 1023)) * 32 + d] = f2bf(v * scale);
                    } else {
                        int c3 = c - 256;
                        if (c3 < 128) {
                            int h = 4 + (c3 >> 5), d = c3 & 31;
                            Kbf[(((size_t)(b * 8 + h) << 10) | (n & 1023)) * 32 + d] = f2bf(v);
                        } else if (c3 < 192) {
                            CVin[(size_t)n * 64 + (c3 - 128)] = v;
                        } else {
                            int h = 2 + ((c3 - 192) >> 5), d = c3 & 31;
                            Kbf[(((size_t)(b * 8 + h) << 10) | (n & 1023)) * 32 + d] = f2bf(v);
                        }
                    }
                }
            } else {
                int c4 = c - 512;
                int h = c4 >> 5, d = c4 & 31;
                short4v pk;
                #pragma unroll
                for (int r = 0; r < 4; ++r) pk[r] = (short)f2bf(acc[fr][fc][r] + bv);
                *(short4v*)&VTbf[((size_t)((b * 8 + h) * 32 + d)) * 1024 + (nb & 1023)] = pk;
            }
        }
}

// ---------------------------------------------------------------------------
// Kernel 4: 3x3 SAME conv, input CVin fp32 [4096][64], output -> Kbf heads 0,1
// ---------------------------------------------------------------------------
__global__ __launch_bounds__(256) void conv3x3_kernel(
    const float* __restrict__ CVin, const float* __restrict__ cw,
    const float* __restrict__ cb, ushort_t* __restrict__ Kbf)
{
    __shared__ float in_s[3][6][64];
    int blk = blockIdx.x;
    int b = blk >> 8, ng = blk & 255;
    int n0 = ng * 4, y = n0 >> 5, x0 = n0 & 31;
    int tid = threadIdx.x;

    for (int idx = tid; idx < 3 * 6 * 64; idx += 256) {
        int ci = idx & 63, rem = idx >> 6, rx = rem % 6, ry = rem / 6;
        int gy = y - 1 + ry, gx = x0 - 1 + rx;
        float v = 0.f;
        if (gy >= 0 && gy < 32 && gx >= 0 && gx < 32)
            v = CVin[((size_t)(b * 1024 + gy * 32 + gx)) * 64 + ci];
        in_s[ry][rx][ci] = v;
    }
    __syncthreads();

    int px = tid >> 6, co = tid & 63;
    float acc = cb[co];
    #pragma unroll
    for (int ky = 0; ky < 3; ++ky)
        #pragma unroll
        for (int kx = 0; kx < 3; ++kx)
            #pragma unroll 8
            for (int ci = 0; ci < 64; ++ci)
                acc += in_s[ky][px + kx][ci] * cw[(((ky * 3 + kx) * 64 + ci) << 6) + co];

    int h = co >> 5, d = co & 31;
    int n = n0 + px;
    Kbf[(((size_t)(b * 8 + h) << 10) | n) * 32 + d] = f2bf(acc);
}

// ---------------------------------------------------------------------------
// Kernel 5: MFMA flash attention, swapped QK^T, no-max softmax, KV split=2.
// grid (16 qtiles, 32 bh, 2 splits). Block = 64 q rows, 4 waves.
// Writes unnormalized partial O (fp32) and partial l.
// ---------------------------------------------------------------------------
__global__ __launch_bounds__(256) void attn_mfma3(
    const ushort_t* __restrict__ Qbf, const ushort_t* __restrict__ Kbf,
    const ushort_t* __restrict__ VTbf,
    float* __restrict__ Opart, float* __restrict__ Lpart)
{
    __shared__ ushort_t Kt[64][32];
    __shared__ ushort_t VT[32][72];
    __shared__ ushort_t Ps[4][16][72];

    int bh = blockIdx.y, q0 = blockIdx.x * 64, s = blockIdx.z;
    int tid = threadIdx.x, w = tid >> 6, l = tid & 63, lr = l & 15, g = l >> 4;

    short8v qfrag = *(const short8v*)&Qbf[((size_t)bh * 1024 + q0 + w * 16 + lr) * 32 + g * 8];

    f32x4 accO[2] = {};
    float lsum = 0.f;
    const f32x4 zero = {};

    for (int mt = s * 8; mt < s * 8 + 8; ++mt) {
        int m0 = mt * 64;
        ((short8v*)&Kt[0][0])[tid] =
            *(const short8v*)&Kbf[((size_t)bh * 1024 + m0) * 32 + tid * 8];
        *(short8v*)&VT[tid >> 3][(tid & 7) * 8] =
            *(const short8v*)&VTbf[((size_t)bh * 32 + (tid >> 3)) * 1024 + m0 + (tid & 7) * 8];
        __syncthreads();

        f32x4 st[4];
        #pragma unroll
        for (int t = 0; t < 4; ++t) {
            short8v kf = *(const short8v*)&Kt[t * 16 + lr][g * 8];
            st[t] = __builtin_amdgcn_mfma_f32_16x16x32_bf16(kf, qfrag, zero, 0, 0, 0);
        }

        #pragma unroll
        for (int t = 0; t < 4; ++t) {
            float p0 = __expf(st[t][0]), p1 = __expf(st[t][1]);
            float p2 = __expf(st[t][2]), p3 = __expf(st[t][3]);
            lsum += (p0 + p1) + (p2 + p3);
            short4v pw;
            pw[0] = (short)f2bf(p0); pw[1] = (short)f2bf(p1);
            pw[2] = (short)f2bf(p2); pw[3] = (short)f2bf(p3);
            *(short4v*)&Ps[w][lr][t * 16 + g * 4] = pw;
        }

        #pragma unroll
        for (int kt = 0; kt < 2; ++kt) {
            short8v pa = *(const short8v*)&Ps[w][lr][kt * 32 + g * 8];
            #pragma unroll
            for (int nt = 0; nt < 2; ++nt) {
                short8v vb = *(const short8v*)&VT[nt * 16 + lr][kt * 32 + g * 8];
                accO[nt] = __builtin_amdgcn_mfma_f32_16x16x32_bf16(pa, vb, accO[nt], 0, 0, 0);
            }
        }
        __syncthreads();
    }

    lsum += __shfl_xor(lsum, 16);
    lsum += __shfl_xor(lsum, 32);
    if (l < 16)
        Lpart[(size_t)(s * 32 + bh) * 1024 + q0 + w * 16 + lr] = lsum;

    #pragma unroll
    for (int nt = 0; nt < 2; ++nt)
        #pragma unroll
        for (int r = 0; r < 4; ++r) {
            int n = q0 + w * 16 + g * 4 + r;
            Opart[((size_t)(s * 32 + bh) * 1024 + n) * 32 + nt * 16 + lr] = accO[nt][r];
        }
}

// ---------------------------------------------------------------------------
// Kernel 6: merge splits: AObf = bf16((O0+O1)/(l0+l1)). grid 1024, 256 thr.
// ---------------------------------------------------------------------------
__global__ __launch_bounds__(256) void attn_merge(
    const float* __restrict__ Opart, const float* __restrict__ Lpart,
    ushort_t* __restrict__ AObf)
{
    int row = blockIdx.x * 32 + (threadIdx.x >> 3);   // bh*1024 + n
    int d0 = (threadIdx.x & 7) * 4;
    const size_t SSTR = (size_t)32 * 1024 * 32;       // split stride (floats)
    float4 o0 = *(const float4*)&Opart[(size_t)row * 32 + d0];
    float4 o1 = *(const float4*)&Opart[SSTR + (size_t)row * 32 + d0];
    float inv = 1.0f / (Lpart[row] + Lpart[32768 + row]);
    int bh = row >> 10, n = row & 1023, b = bh >> 3, h = bh & 7;
    short4v pk;
    pk[0] = (short)f2bf((o0.x + o1.x) * inv);
    pk[1] = (short)f2bf((o0.y + o1.y) * inv);
    pk[2] = (short)f2bf((o0.z + o1.z) * inv);
    pk[3] = (short)f2bf((o0.w + o1.w) * inv);
    *(short4v*)&AObf[((size_t)(b * 1024 + n)) * 256 + h * 32 + d0] = pk;
}

// ---------------------------------------------------------------------------
// Kernel 7: output GEMM  out = AObf @ Wo + bo (fp32 out). 64x64 tile.
// ---------------------------------------------------------------------------
__global__ __launch_bounds__(256) void out_gemm(
    const ushort_t* __restrict__ A, const ushort_t* __restrict__ WoT,
    const float* __restrict__ bo, float* __restrict__ out)
{
    __shared__ ushort_t As[64][136];
    __shared__ ushort_t Bs[64][136];
    int colBase = blockIdx.x * 64, rowBase = blockIdx.y * 64;
    int tid = threadIdx.x;
    int w = tid >> 6, l = tid & 63, lr = l & 15, g = l >> 4;
    int wr = w >> 1, wc = w & 1;
    int tr = tid >> 2, tq = tid & 3;
    f32x4 acc[2][2] = {};

    for (int kb = 0; kb < 256; kb += 128) {
        #pragma unroll
        for (int i = 0; i < 4; ++i)
            *(short8v*)&As[tr][tq * 32 + i * 8] =
                *(const short8v*)&A[(size_t)(rowBase + tr) * 256 + kb + tq * 32 + i * 8];
        #pragma unroll
        for (int i = 0; i < 4; ++i)
            *(short8v*)&Bs[tr][tq * 32 + i * 8] =
                *(const short8v*)&WoT[(size_t)(colBase + tr) * 256 + kb + tq * 32 + i * 8];
        __syncthreads();
        #pragma unroll
        for (int ks = 0; ks < 4; ++ks) {
            short8v a0 = *(const short8v*)&As[wr * 32 + lr][ks * 32 + g * 8];
            short8v a1 = *(const short8v*)&As[wr * 32 + 16 + lr][ks * 32 + g * 8];
            short8v b0 = *(const short8v*)&Bs[wc * 32 + lr][ks * 32 + g * 8];
            short8v b1 = *(const short8v*)&Bs[wc * 32 + 16 + lr][ks * 32 + g * 8];
            acc[0][0] = __builtin_amdgcn_mfma_f32_16x16x32_bf16(a0, b0, acc[0][0], 0, 0, 0);
            acc[0][1] = __builtin_amdgcn_mfma_f32_16x16x32_bf16(a0, b1, acc[0][1], 0, 0, 0);
            acc[1][0] = __builtin_amdgcn_mfma_f32_16x16x32_bf16(a1, b0, acc[1][0], 0, 0, 0);
            acc[1][1] = __builtin_amdgcn_mfma_f32_16x16x32_bf16(a1, b1, acc[1][1], 0, 0, 0);
        }
        __syncthreads();
    }

    #pragma unroll
    for (int fr = 0; fr < 2; ++fr)
        #pragma unroll
        for (int fc = 0; fc < 2; ++fc) {
            int c = colBase + wc * 32 + fc * 16 + lr;
            float bv = bo[c];
            int nb = rowBase + wr * 32 + fr * 16 + g * 4;
            #pragma unroll
            for (int r = 0; r < 4; ++r)
                out[(size_t)(nb + r) * 256 + c] = acc[fr][fc][r] + bv;
        }
}

// ---------------------------------------------------------------------------
extern "C" void kernel_launch(void* const* d_in, const int* in_sizes, int n_in,
                              void* d_out, int out_size, void* d_ws, size_t ws_size,
                              hipStream_t stream)
{
    const float* src1 = (const float*)d_in[0];
    const float* src2 = (const float*)d_in[1];
    const float* Wq1  = (const float*)d_in[2];
    const float* bq1  = (const float*)d_in[3];
    const float* Wq2  = (const float*)d_in[4];
    const float* bq2  = (const float*)d_in[5];
    const float* Wk   = (const float*)d_in[6];
    const float* bk   = (const float*)d_in[7];
    const float* Wv   = (const float*)d_in[8];
    const float* bv   = (const float*)d_in[9];
    const float* cw   = (const float*)d_in[10];
    const float* cb   = (const float*)d_in[11];
    const float* Wo   = (const float*)d_in[12];
    const float* bo   = (const float*)d_in[13];
    float* out = (float*)d_out;

    char* base = (char*)d_ws;
    const size_t MB = 1u << 20;
    ushort_t* X1bf = (ushort_t*)(base + 0 * MB);     // 2 MB
    ushort_t* X2bf = (ushort_t*)(base + 2 * MB);     // 2 MB
    ushort_t* Qbf  = (ushort_t*)(base + 4 * MB);     // 2 MB  [32 bh][1024][32]
    ushort_t* Kbf  = (ushort_t*)(base + 6 * MB);     // 2 MB
    ushort_t* VTbf = (ushort_t*)(base + 8 * MB);     // 2 MB  [32 bh][32][1024]
    ushort_t* AObf = (ushort_t*)(base + 10 * MB);    // 2 MB  [4096][256]
    float*    CVin = (float*)(base + 12 * MB);       // 1 MB  [4096][64]
    ushort_t* WcatT= (ushort_t*)(base + 13 * MB);    // 384 KB [768][256]
    ushort_t* WoT  = (ushort_t*)(base + 13 * MB + 384 * 1024);  // 128 KB
    float*    bcat = (float*)(base + 13 * MB + 512 * 1024);     // 3 KB
    float*    Opart= (float*)(base + 14 * MB);       // 8 MB  [2][32][1024][32]
    float*    Lpart= (float*)(base + 22 * MB);       // 256 KB [2][32][1024]

    pe_add_bf16<<<1024, 256, 0, stream>>>(src1, src2, X1bf, X2bf);
    prep_weights<<<dim3(4, 16), 256, 0, stream>>>(
        Wq1, Wq2, Wk, Wv, Wo, bq1, bq2, bk, bv, WcatT, WoT, bcat);
    proj_gemm<<<dim3(12, 64), 256, 0, stream>>>(
        X1bf, X2bf, WcatT, bcat, Qbf, Kbf, VTbf, CVin);
    conv3x3_kernel<<<1024, 256, 0, stream>>>(CVin, cw, cb, Kbf);
    attn_mfma3<<<dim3(16, 32, 2), 256, 0, stream>>>(Qbf, Kbf, VTbf, Opart, Lpart);
    attn_merge<<<1024, 256, 0, stream>>>(Opart, Lpart, AObf);
    out_gemm<<<dim3(4, 64), 256, 0, stream>>>(AObf, WoT, bo, out);
}